// Round 1
// baseline (353.942 us; speedup 1.0000x reference)
//
#include <hip/hip_runtime.h>

#define H 32

// ---------------- Kernel 1: encoder  h = relu(x @ W + b) ----------------
// One 32-lane group per node; lane = output channel. Weights staged in LDS.
template<int FIN>
__global__ void encoder_kernel(const float* __restrict__ x,
                               const float* __restrict__ W,
                               const float* __restrict__ b,
                               float* __restrict__ h, int N) {
    __shared__ float sW[FIN * H];
    __shared__ float sb[H];
    int t = threadIdx.x;
    for (int i = t; i < FIN * H; i += blockDim.x) sW[i] = W[i];
    if (t < H) sb[t] = b[t];
    __syncthreads();

    int lane  = t & (H - 1);
    int local = t >> 5;                       // node within block (8 per 256 thr)
    long long node = (long long)blockIdx.x * (blockDim.x / H) + local;
    if (node >= N) return;

    const float* xr = x + node * FIN;
    float acc = sb[lane];
    #pragma unroll
    for (int k = 0; k < FIN; ++k)
        acc = fmaf(xr[k], sW[k * H + lane], acc);   // xr[k] broadcast in group
    h[node * H + lane] = fmaxf(acc, 0.0f);
}

// ---------------- Kernel 2: scatter-add messages ----------------
// Half-wave (32 lanes) per edge; lane = channel. sum[dst] += h_src[src].
__global__ void scatter_kernel(const float* __restrict__ h_src,
                               const int* __restrict__ src,
                               const int* __restrict__ dst,
                               float* __restrict__ sum,
                               float* __restrict__ cnt,
                               int E) {
    long long t = (long long)blockIdx.x * blockDim.x + threadIdx.x;
    int  lane = (int)(t & (H - 1));
    long long e = t >> 5;
    if (e >= E) return;
    int s = src[e];
    int d = dst[e];
    float v = h_src[(long long)s * H + lane];
    atomicAdd(&sum[(long long)d * H + lane], v);
    if (lane == 0) atomicAdd(&cnt[d], 1.0f);
}

// ---------------- Kernel 3: fused head ----------------
// out[i] = relu( mean_rb @ Wl_rb + mean_bb @ Wl_bb + h_b @ (Wr_rb+Wr_bb)
//                + (bl_rb+bl_bb) ) @ Wo + bo
// One 32-lane group per node; lane = hidden channel; shfl-broadcast operands.
__global__ void head_kernel(const float* __restrict__ h_b,
                            const float* __restrict__ sum_rb,
                            const float* __restrict__ sum_bb,
                            const float* __restrict__ cnt_rb,
                            const float* __restrict__ cnt_bb,
                            const float* __restrict__ Wl_rb,
                            const float* __restrict__ bl_rb,
                            const float* __restrict__ Wl_bb,
                            const float* __restrict__ bl_bb,
                            const float* __restrict__ Wr_rb,
                            const float* __restrict__ Wr_bb,
                            const float* __restrict__ Wo,
                            const float* __restrict__ bo,
                            float* __restrict__ y, int N) {
    __shared__ float sWl_rb[H * H];
    __shared__ float sWl_bb[H * H];
    __shared__ float sWr[H * H];
    __shared__ float sbl[H];
    __shared__ float sWo[H];
    __shared__ float sbo;

    int t = threadIdx.x;
    for (int i = t; i < H * H; i += blockDim.x) {
        sWl_rb[i] = Wl_rb[i];
        sWl_bb[i] = Wl_bb[i];
        sWr[i]    = Wr_rb[i] + Wr_bb[i];
    }
    if (t < H) {
        sbl[t] = bl_rb[t] + bl_bb[t];
        sWo[t] = Wo[t];
    }
    if (t == 0) sbo = bo[0];
    __syncthreads();

    int lane  = t & (H - 1);
    int local = t >> 5;
    long long node = (long long)blockIdx.x * (blockDim.x / H) + local;
    if (node >= N) return;

    float inv_rb = 1.0f / fmaxf(cnt_rb[node], 1.0f);
    float inv_bb = 1.0f / fmaxf(cnt_bb[node], 1.0f);

    float v_rb = sum_rb[node * H + lane] * inv_rb;   // mean_rb[lane]
    float v_bb = sum_bb[node * H + lane] * inv_bb;   // mean_bb[lane]
    float v_hb = h_b[node * H + lane];               // h_b[lane]

    float acc = sbl[lane];
    #pragma unroll
    for (int k = 0; k < H; ++k) {
        acc = fmaf(__shfl(v_rb, k, 32), sWl_rb[k * H + lane], acc);
        acc = fmaf(__shfl(v_bb, k, 32), sWl_bb[k * H + lane], acc);
        acc = fmaf(__shfl(v_hb, k, 32), sWr[k * H + lane], acc);
    }
    float r = fmaxf(acc, 0.0f);

    // 32-lane dot with Wo
    float p = r * sWo[lane];
    #pragma unroll
    for (int off = 16; off; off >>= 1) p += __shfl_xor(p, off, 32);
    if (lane == 0) y[node] = p + sbo;
}

extern "C" void kernel_launch(void* const* d_in, const int* in_sizes, int n_in,
                              void* d_out, int out_size, void* d_ws, size_t ws_size,
                              hipStream_t stream) {
    const float* x_bridge = (const float*)d_in[0];
    const float* x_road   = (const float*)d_in[1];
    // d_in[2], d_in[3]: src_br/dst_br — dead code in reference, skipped.
    const int* src_rb = (const int*)d_in[4];
    const int* dst_rb = (const int*)d_in[5];
    const int* src_bb = (const int*)d_in[6];
    const int* dst_bb = (const int*)d_in[7];
    const float* W_enc_b = (const float*)d_in[8];
    const float* b_enc_b = (const float*)d_in[9];
    const float* W_enc_r = (const float*)d_in[10];
    const float* b_enc_r = (const float*)d_in[11];
    // 12,13,14: Wl_br/bl_br/Wr_br — dead.
    const float* Wl_rb = (const float*)d_in[15];
    const float* bl_rb = (const float*)d_in[16];
    const float* Wr_rb = (const float*)d_in[17];
    const float* Wl_bb = (const float*)d_in[18];
    const float* bl_bb = (const float*)d_in[19];
    const float* Wr_bb = (const float*)d_in[20];
    const float* Wo = (const float*)d_in[21];
    const float* bo = (const float*)d_in[22];
    float* y = (float*)d_out;

    const int NB = in_sizes[0] / 16;
    const int NR = in_sizes[1] / 8;
    const int E_RB = in_sizes[4];
    const int E_BB = in_sizes[6];

    // Workspace layout (floats):
    float* ws = (float*)d_ws;
    float* h_b    = ws;                               // NB*H
    float* h_r    = h_b + (size_t)NB * H;             // NR*H
    float* sum_rb = h_r + (size_t)NR * H;             // NB*H
    float* sum_bb = sum_rb + (size_t)NB * H;          // NB*H
    float* cnt_rb = sum_bb + (size_t)NB * H;          // NB
    float* cnt_bb = cnt_rb + NB;                      // NB

    // Zero the accumulator region (sum_rb..cnt_bb) — contiguous.
    size_t zero_bytes = ((size_t)NB * H * 2 + (size_t)NB * 2) * sizeof(float);
    hipMemsetAsync(sum_rb, 0, zero_bytes, stream);

    // Encoders
    {
        int blocks = (NB + 7) / 8;
        encoder_kernel<16><<<blocks, 256, 0, stream>>>(x_bridge, W_enc_b, b_enc_b, h_b, NB);
    }
    {
        int blocks = (NR + 7) / 8;
        encoder_kernel<8><<<blocks, 256, 0, stream>>>(x_road, W_enc_r, b_enc_r, h_r, NR);
    }

    // Scatter rb: road -> bridge (uses h_r)
    {
        long long threads = (long long)E_RB * H;
        int blocks = (int)((threads + 255) / 256);
        scatter_kernel<<<blocks, 256, 0, stream>>>(h_r, src_rb, dst_rb, sum_rb, cnt_rb, E_RB);
    }
    // Scatter bb: bridge -> bridge (uses h_b)
    {
        long long threads = (long long)E_BB * H;
        int blocks = (int)((threads + 255) / 256);
        scatter_kernel<<<blocks, 256, 0, stream>>>(h_b, src_bb, dst_bb, sum_bb, cnt_bb, E_BB);
    }

    // Fused head
    {
        int blocks = (NB + 7) / 8;
        head_kernel<<<blocks, 256, 0, stream>>>(h_b, sum_rb, sum_bb, cnt_rb, cnt_bb,
                                                Wl_rb, bl_rb, Wl_bb, bl_bb,
                                                Wr_rb, Wr_bb, Wo, bo, y, NB);
    }
}

// Round 2
// 310.799 us; speedup vs baseline: 1.1388x; 1.1388x over previous
//
#include <hip/hip_runtime.h>

#define H 32
#define SCAN_CHUNK 1024   // elements per scan block (256 threads x 4)

// ---------------- Kernel 1: encoder  h = relu(x @ W + b) ----------------
template<int FIN>
__global__ void encoder_kernel(const float* __restrict__ x,
                               const float* __restrict__ W,
                               const float* __restrict__ b,
                               float* __restrict__ h, int N) {
    __shared__ float sW[FIN * H];
    __shared__ float sb[H];
    int t = threadIdx.x;
    for (int i = t; i < FIN * H; i += blockDim.x) sW[i] = W[i];
    if (t < H) sb[t] = b[t];
    __syncthreads();

    int lane  = t & (H - 1);
    int local = t >> 5;
    long long node = (long long)blockIdx.x * (blockDim.x / H) + local;
    if (node >= N) return;

    const float* xr = x + node * FIN;
    float acc = sb[lane];
    #pragma unroll
    for (int k = 0; k < FIN; ++k)
        acc = fmaf(xr[k], sW[k * H + lane], acc);
    h[node * H + lane] = fmaxf(acc, 0.0f);
}

// ---------------- CSR build: histogram over concatenated dst space ----------------
// dst slot: rb edges -> [0,NB), bb edges -> [NB, 2NB)
__global__ void hist_kernel(const int* __restrict__ dst_rb,
                            const int* __restrict__ dst_bb,
                            int* __restrict__ deg,
                            int E_RB, int E_BB, int NB) {
    long long e = (long long)blockIdx.x * blockDim.x + threadIdx.x;
    if (e < E_RB) {
        atomicAdd(&deg[dst_rb[e]], 1);
    } else if (e < (long long)E_RB + E_BB) {
        atomicAdd(&deg[NB + dst_bb[e - E_RB]], 1);
    }
}

// ---------------- Scan pass A: per-chunk sums ----------------
__global__ void scanA_kernel(const int* __restrict__ deg, int* __restrict__ psum, int N2) {
    __shared__ int red[256];
    int b = blockIdx.x, t = threadIdx.x;
    long long i0 = (long long)b * SCAN_CHUNK + t * 4;
    int s = 0;
    #pragma unroll
    for (int j = 0; j < 4; ++j) {
        long long i = i0 + j;
        if (i < N2) s += deg[i];
    }
    red[t] = s;
    __syncthreads();
    for (int off = 128; off; off >>= 1) {
        if (t < off) red[t] += red[t + off];
        __syncthreads();
    }
    if (t == 0) psum[b] = red[0];
}

// ---------------- Scan pass B: exclusive scan of chunk sums (1 block) ----------------
__global__ void scanB_kernel(const int* __restrict__ psum, int* __restrict__ chunk_off,
                             int nchunks) {
    __shared__ int tmp[256];
    int t = threadIdx.x;
    int carry = 0;
    for (int s0 = 0; s0 < nchunks; s0 += 256) {
        int v = (s0 + t < nchunks) ? psum[s0 + t] : 0;
        tmp[t] = v;
        __syncthreads();
        for (int off = 1; off < 256; off <<= 1) {
            int x = (t >= off) ? tmp[t - off] : 0;
            __syncthreads();
            tmp[t] += x;
            __syncthreads();
        }
        if (s0 + t < nchunks) chunk_off[s0 + t] = carry + tmp[t] - v;  // exclusive
        carry += tmp[255];
        __syncthreads();
    }
}

// ---------------- Scan pass C: per-element exclusive prefix -> base ----------------
__global__ void scanC_kernel(const int* __restrict__ deg,
                             const int* __restrict__ chunk_off,
                             int* __restrict__ base_, int N2) {
    __shared__ int tmp[256];
    int b = blockIdx.x, t = threadIdx.x;
    long long i0 = (long long)b * SCAN_CHUNK + t * 4;
    int v[4];
    int s = 0;
    #pragma unroll
    for (int j = 0; j < 4; ++j) {
        long long i = i0 + j;
        v[j] = (i < N2) ? deg[i] : 0;
        s += v[j];
    }
    tmp[t] = s;
    __syncthreads();
    for (int off = 1; off < 256; off <<= 1) {
        int x = (t >= off) ? tmp[t - off] : 0;
        __syncthreads();
        tmp[t] += x;
        __syncthreads();
    }
    int run = chunk_off[b] + tmp[t] - s;  // exclusive prefix for this thread's 4 elems
    #pragma unroll
    for (int j = 0; j < 4; ++j) {
        long long i = i0 + j;
        if (i < N2) base_[i] = run;
        run += v[j];
    }
}

// ---------------- CSR fill: permute edge srcs into dst-grouped slots ----------------
__global__ void fill_kernel(const int* __restrict__ src_rb, const int* __restrict__ dst_rb,
                            const int* __restrict__ src_bb, const int* __restrict__ dst_bb,
                            const int* __restrict__ base_, int* __restrict__ cur,
                            int* __restrict__ edge_src,
                            int E_RB, int E_BB, int NB) {
    long long e = (long long)blockIdx.x * blockDim.x + threadIdx.x;
    int s, d;
    if (e < E_RB) {
        s = src_rb[e]; d = dst_rb[e];
    } else if (e < (long long)E_RB + E_BB) {
        long long e2 = e - E_RB;
        s = src_bb[e2]; d = NB + dst_bb[e2];
    } else return;
    int slot = base_[d] + atomicAdd(&cur[d], 1);
    edge_src[slot] = s;
}

// ---------------- Gather: per-(relation,node) mean, zero atomics ----------------
__global__ void gather_kernel(const float* __restrict__ h_r,
                              const float* __restrict__ h_b,
                              const int* __restrict__ base_,
                              const int* __restrict__ deg,
                              const int* __restrict__ edge_src,
                              float* __restrict__ mean, int NB) {
    int t = threadIdx.x;
    int lane  = t & (H - 1);
    int local = t >> 5;
    long long g = (long long)blockIdx.x * (blockDim.x / H) + local;
    if (g >= 2LL * NB) return;

    const float* __restrict__ hs = (g < NB) ? h_r : h_b;
    int b0 = base_[g];
    int dg = deg[g];
    float acc = 0.0f;
    int k = 0;
    for (; k + 4 <= dg; k += 4) {
        int s0 = edge_src[b0 + k];
        int s1 = edge_src[b0 + k + 1];
        int s2 = edge_src[b0 + k + 2];
        int s3 = edge_src[b0 + k + 3];
        float a0 = hs[(long long)s0 * H + lane];
        float a1 = hs[(long long)s1 * H + lane];
        float a2 = hs[(long long)s2 * H + lane];
        float a3 = hs[(long long)s3 * H + lane];
        acc += a0 + a1 + a2 + a3;
    }
    for (; k < dg; ++k)
        acc += hs[(long long)edge_src[b0 + k] * H + lane];

    mean[g * H + lane] = acc / fmaxf((float)dg, 1.0f);
}

// ---------------- Fused head ----------------
// out[i] = relu( mean_rb @ Wl_rb + mean_bb @ Wl_bb + h_b @ (Wr_rb+Wr_bb)
//                + (bl_rb+bl_bb) ) @ Wo + bo
__global__ void head_kernel(const float* __restrict__ h_b,
                            const float* __restrict__ mean,   // [2NB, H]
                            const float* __restrict__ Wl_rb,
                            const float* __restrict__ bl_rb,
                            const float* __restrict__ Wl_bb,
                            const float* __restrict__ bl_bb,
                            const float* __restrict__ Wr_rb,
                            const float* __restrict__ Wr_bb,
                            const float* __restrict__ Wo,
                            const float* __restrict__ bo,
                            float* __restrict__ y, int N) {
    __shared__ float sWl_rb[H * H];
    __shared__ float sWl_bb[H * H];
    __shared__ float sWr[H * H];
    __shared__ float sbl[H];
    __shared__ float sWo[H];
    __shared__ float sbo;

    int t = threadIdx.x;
    for (int i = t; i < H * H; i += blockDim.x) {
        sWl_rb[i] = Wl_rb[i];
        sWl_bb[i] = Wl_bb[i];
        sWr[i]    = Wr_rb[i] + Wr_bb[i];
    }
    if (t < H) {
        sbl[t] = bl_rb[t] + bl_bb[t];
        sWo[t] = Wo[t];
    }
    if (t == 0) sbo = bo[0];
    __syncthreads();

    int lane  = t & (H - 1);
    int local = t >> 5;
    long long node = (long long)blockIdx.x * (blockDim.x / H) + local;
    if (node >= N) return;

    float v_rb = mean[node * H + lane];
    float v_bb = mean[((long long)N + node) * H + lane];
    float v_hb = h_b[node * H + lane];

    float acc = sbl[lane];
    #pragma unroll
    for (int k = 0; k < H; ++k) {
        acc = fmaf(__shfl(v_rb, k, 32), sWl_rb[k * H + lane], acc);
        acc = fmaf(__shfl(v_bb, k, 32), sWl_bb[k * H + lane], acc);
        acc = fmaf(__shfl(v_hb, k, 32), sWr[k * H + lane], acc);
    }
    float r = fmaxf(acc, 0.0f);

    float p = r * sWo[lane];
    #pragma unroll
    for (int off = 16; off; off >>= 1) p += __shfl_xor(p, off, 32);
    if (lane == 0) y[node] = p + sbo;
}

extern "C" void kernel_launch(void* const* d_in, const int* in_sizes, int n_in,
                              void* d_out, int out_size, void* d_ws, size_t ws_size,
                              hipStream_t stream) {
    const float* x_bridge = (const float*)d_in[0];
    const float* x_road   = (const float*)d_in[1];
    const int* src_rb = (const int*)d_in[4];
    const int* dst_rb = (const int*)d_in[5];
    const int* src_bb = (const int*)d_in[6];
    const int* dst_bb = (const int*)d_in[7];
    const float* W_enc_b = (const float*)d_in[8];
    const float* b_enc_b = (const float*)d_in[9];
    const float* W_enc_r = (const float*)d_in[10];
    const float* b_enc_r = (const float*)d_in[11];
    const float* Wl_rb = (const float*)d_in[15];
    const float* bl_rb = (const float*)d_in[16];
    const float* Wr_rb = (const float*)d_in[17];
    const float* Wl_bb = (const float*)d_in[18];
    const float* bl_bb = (const float*)d_in[19];
    const float* Wr_bb = (const float*)d_in[20];
    const float* Wo = (const float*)d_in[21];
    const float* bo = (const float*)d_in[22];
    float* y = (float*)d_out;

    const int NB = in_sizes[0] / 16;
    const int NR = in_sizes[1] / 8;
    const int E_RB = in_sizes[4];
    const int E_BB = in_sizes[6];
    const int N2 = 2 * NB;
    const long long E_ALL = (long long)E_RB + E_BB;
    const int nchunks = (N2 + SCAN_CHUNK - 1) / SCAN_CHUNK;

    // Workspace layout
    char* wp = (char*)d_ws;
    float* h_b  = (float*)wp;  wp += (size_t)NB * H * sizeof(float);
    float* h_r  = (float*)wp;  wp += (size_t)NR * H * sizeof(float);
    float* mean = (float*)wp;  wp += (size_t)N2 * H * sizeof(float);
    int* deg       = (int*)wp; wp += (size_t)N2 * sizeof(int);
    int* cur       = (int*)wp; wp += (size_t)N2 * sizeof(int);   // contiguous after deg
    int* base_     = (int*)wp; wp += (size_t)N2 * sizeof(int);
    int* psum      = (int*)wp; wp += (size_t)nchunks * sizeof(int);
    int* chunk_off = (int*)wp; wp += (size_t)nchunks * sizeof(int);
    int* edge_src  = (int*)wp; wp += (size_t)E_ALL * sizeof(int);

    // Zero deg + cur (contiguous)
    hipMemsetAsync(deg, 0, (size_t)N2 * 2 * sizeof(int), stream);

    // Encoders
    encoder_kernel<16><<<(NB + 7) / 8, 256, 0, stream>>>(x_bridge, W_enc_b, b_enc_b, h_b, NB);
    encoder_kernel<8><<<(NR + 7) / 8, 256, 0, stream>>>(x_road, W_enc_r, b_enc_r, h_r, NR);

    // CSR build
    int eblocks = (int)((E_ALL + 255) / 256);
    hist_kernel<<<eblocks, 256, 0, stream>>>(dst_rb, dst_bb, deg, E_RB, E_BB, NB);
    scanA_kernel<<<nchunks, 256, 0, stream>>>(deg, psum, N2);
    scanB_kernel<<<1, 256, 0, stream>>>(psum, chunk_off, nchunks);
    scanC_kernel<<<nchunks, 256, 0, stream>>>(deg, chunk_off, base_, N2);
    fill_kernel<<<eblocks, 256, 0, stream>>>(src_rb, dst_rb, src_bb, dst_bb,
                                             base_, cur, edge_src, E_RB, E_BB, NB);

    // Gather means (no atomics)
    gather_kernel<<<(N2 + 7) / 8, 256, 0, stream>>>(h_r, h_b, base_, deg, edge_src, mean, NB);

    // Fused head
    head_kernel<<<(NB + 7) / 8, 256, 0, stream>>>(h_b, mean,
                                                  Wl_rb, bl_rb, Wl_bb, bl_bb,
                                                  Wr_rb, Wr_bb, Wo, bo, y, NB);
}